// Round 12
// baseline (161.009 us; speedup 1.0000x reference)
//
#include <hip/hip_runtime.h>

// CapsuleFC: B=64, N=128, A=64, M=128, D=64
// out = [ncv (B*M*D) | na (B*M) | qk (B*N*M)], fp32
// R12: depth-3 DMA pipeline. 512-thr blocks, 4x32KB LDS ring (1 block/CU),
// grid (32,8) = 256 blocks = 1/CU. stage(h+3) issued per phase, vmcnt(4)
// steady-state -> 2-3 phases of latency cover. av loads E/O double-buffered
// one phase ahead, always issued BEFORE the tile DMAs (in-order vmcnt).
typedef __attribute__((ext_vector_type(8))) short bf16x8;
typedef __attribute__((ext_vector_type(4))) float f32x4;

constexpr int Bq = 64, Nq = 128, Aq = 64, Mq = 128, Dq = 64;
constexpr int MD = Mq * Dq;    // 8192
constexpr int NM = Nq * Mq;    // 16384
constexpr int NA = Nq * Aq;    // 8192
constexpr int NCV_SZ = Bq * MD;   // 524288
constexpr int NA_SZ  = Bq * Mq;   // 8192
constexpr float SCALE = 0.125f;   // 1/sqrt(64)

__device__ __forceinline__ unsigned short f2b(float f) {  // fp32 -> bf16 RNE
  unsigned u = __float_as_uint(f);
  return (unsigned short)((u + 0x7fffu + ((u >> 16) & 1u)) >> 16);
}
__device__ __forceinline__ unsigned cvt2(float lo, float hi) {
  return ((unsigned)f2b(hi) << 16) | (unsigned)f2b(lo);
}
__device__ __forceinline__ bf16x8 pack8(const float* v) {
  union { unsigned u[4]; bf16x8 b; } x;
  x.u[0] = cvt2(v[0], v[1]); x.u[1] = cvt2(v[2], v[3]);
  x.u[2] = cvt2(v[4], v[5]); x.u[3] = cvt2(v[6], v[7]);
  return x.b;
}
__device__ __forceinline__ void dma16(const float* g, float* l) {
  __builtin_amdgcn_global_load_lds(
      (const __attribute__((address_space(1))) unsigned*)g,
      (__attribute__((address_space(3))) unsigned*)l, 16, 0, 0);
}

// ---------------- init: ncv = 0, na = 1 ----------------
__global__ __launch_bounds__(256) void k0_init(float* __restrict__ out) {
  int i = blockIdx.x * 256 + threadIdx.x;
  if (i < NCV_SZ) out[i] = 0.0f;
  else if (i < NCV_SZ + NA_SZ) out[i] = 1.0f;
}

// ---------------- K1: logits, depth-3 pipelined MFMA ----------------
// grid (mc=32, ns=8), block 512. Wave w8 = (wv_b, wv_m): m = mc*4+wv_m,
// b-half 32*wv_b. 16 n's per block, 32 half-tile phases, descending walk.
__global__ __launch_bounds__(512, 2) void k1_logits(
    const float* __restrict__ input, const float* __restrict__ ncvin,
    const float* __restrict__ wgt, float* __restrict__ logits) {
  const int mc = blockIdx.x;
  const int n0 = blockIdx.y * 16;
  const int t = threadIdx.x;
  const int w8 = t >> 6, l = t & 63;
  const int wv_m = w8 & 3, wv_b = w8 >> 2;
  const int lr = l & 15, g = l >> 4;
  const int m = mc * 4 + wv_m;
  __shared__ float Wf[4][32 * 256];   // 128 KB quad ring

  // preload ncvin fragment (epilogue is then vmcnt-free)
  float cnv[2][4][4];
#pragma unroll
  for (int i = 0; i < 2; ++i)
#pragma unroll
    for (int j = 0; j < 4; ++j)
#pragma unroll
      for (int r = 0; r < 4; ++r)
        cnv[i][j][r] = ncvin[(size_t)(32 * wv_b + 16 * i + 4 * g + r) * MD + m * Dq + 16 * j + lr];

  auto stageT = [&](int h) {           // descending walk: hh = 31-h
    if (h > 31) return;
    const int hh = 31 - h;
    const int nn = n0 + (hh >> 1);
    const int ks = (hh & 1) * 32;
    float* dst = &Wf[h & 3][0];
#pragma unroll
    for (int rr = 0; rr < 4; ++rr) {
      const int al = w8 * 4 + rr;
      const char* gs = (const char*)(wgt + (size_t)(nn * Aq + ks + al) * MD + mc * 256)
                       + ((l * 16) ^ (((al >> 3) & 1) << 6));
      dma16((const float*)gs, dst + al * 256);
    }
  };
  auto loadAv = [&](int h, float (&av)[2][8]) {
    if (h > 31) return;
    const int hh = 31 - h;
    const int nn = n0 + (hh >> 1);
    const int ks = (hh & 1) * 32;
#pragma unroll
    for (int i = 0; i < 2; ++i) {
      const float* ap = input + (size_t)(32 * wv_b + 16 * i + lr) * NA + nn * Aq + ks + g * 8;
      *(float4*)&av[i][0] = *(const float4*)ap;
      *(float4*)&av[i][4] = *(const float4*)(ap + 4);
    }
  };
  auto mfmaPhase = [&](int h, float (&av)[2][8], f32x4 (&acc)[2][4]) {
    bf16x8 af[2];
#pragma unroll
    for (int i = 0; i < 2; ++i) af[i] = pack8(av[i]);
    const float* bufp = &Wf[h & 3][0];
#pragma unroll
    for (int j = 0; j < 4; ++j) {
      const int cx = (64 * wv_m + 16 * j + lr) ^ ((g & 1) << 4);
      float bv[8];
#pragma unroll
      for (int e = 0; e < 8; ++e) bv[e] = bufp[(g * 8 + e) * 256 + cx];
      bf16x8 bf = pack8(bv);
#pragma unroll
      for (int i = 0; i < 2; ++i)
        acc[i][j] = __builtin_amdgcn_mfma_f32_16x16x32_bf16(af[i], bf, acc[i][j], 0, 0, 0);
    }
  };

  float avE[2][8], avO[2][8];
  stageT(0);
  loadAv(0, avE);      // av(0) BEFORE tiles 1,2 so draining it costs nothing
  stageT(1);
  stageT(2);

  f32x4 acc[2][4];
  for (int hp = 0; hp < 16; ++hp) {
    const int h0 = hp * 2, h1 = h0 + 1;
    // ---- even phase h0: retire T(h0)+av(h0); keep 2-3 tiles in flight ----
    if (hp == 0)      asm volatile("s_waitcnt vmcnt(8)" ::: "memory");
    else if (hp < 15) asm volatile("s_waitcnt vmcnt(4)" ::: "memory");
    else              asm volatile("s_waitcnt vmcnt(0)" ::: "memory");
    __builtin_amdgcn_s_barrier();
#pragma unroll
    for (int i = 0; i < 2; ++i)
#pragma unroll
      for (int j = 0; j < 4; ++j) acc[i][j] = (f32x4)(0.0f);
    mfmaPhase(h0, avE, acc);
    __builtin_amdgcn_sched_barrier(0);
    loadAv(h1, avO);                  // av before next tile DMAs
    __builtin_amdgcn_sched_barrier(0);
    stageT(h0 + 3);
    // ---- odd phase h1 ----
    if (hp < 15) asm volatile("s_waitcnt vmcnt(4)" ::: "memory");
    else         asm volatile("s_waitcnt vmcnt(0)" ::: "memory");
    __builtin_amdgcn_s_barrier();
    mfmaPhase(h1, avO, acc);
    {   // epilogue for this nn (register-only + shfl + one store)
      const int nn = n0 + ((31 - h1) >> 1);
      float lp[2][4];
#pragma unroll
      for (int i = 0; i < 2; ++i)
#pragma unroll
        for (int r = 0; r < 4; ++r) lp[i][r] = 0.0f;
#pragma unroll
      for (int i = 0; i < 2; ++i)
#pragma unroll
        for (int j = 0; j < 4; ++j)
#pragma unroll
          for (int r = 0; r < 4; ++r)
            lp[i][r] = fmaf(acc[i][j][r], cnv[i][j][r], lp[i][r]);
#pragma unroll
      for (int off = 1; off < 16; off <<= 1)
#pragma unroll
        for (int i = 0; i < 2; ++i)
#pragma unroll
          for (int r = 0; r < 4; ++r) lp[i][r] += __shfl_xor(lp[i][r], off);
      float ov = lp[0][0];
#pragma unroll
      for (int i = 0; i < 2; ++i)
#pragma unroll
        for (int r = 0; r < 4; ++r)
          ov = (lr == i * 4 + r) ? lp[i][r] : ov;
      if (lr < 8) {
        const int b = 32 * wv_b + 16 * (lr >> 2) + 4 * g + (lr & 3);
        logits[(size_t)b * NM + (size_t)nn * Mq + m] = SCALE * ov;
      }
    }
    __builtin_amdgcn_sched_barrier(0);
    loadAv(h0 + 2, avE);
    __builtin_amdgcn_sched_barrier(0);
    stageT(h1 + 3);
  }
}

// ---------------- K2: softmax + act modulation + renorm (in place) ----------------
__global__ __launch_bounds__(256) void k2_softmax(
    const float* __restrict__ next_act, float* __restrict__ qk) {
  const int row  = blockIdx.x * 4 + (threadIdx.x >> 6);
  const int lane = threadIdx.x & 63;
  const int b = row >> 7;
  float* p = qk + (size_t)row * Mq;
  float x0 = p[lane], x1 = p[lane + 64];
  float mx = fmaxf(x0, x1);
#pragma unroll
  for (int off = 32; off; off >>= 1) mx = fmaxf(mx, __shfl_xor(mx, off));
  float e0 = __expf(x0 - mx), e1 = __expf(x1 - mx);
  float s = e0 + e1;
#pragma unroll
  for (int off = 32; off; off >>= 1) s += __shfl_xor(s, off);
  float a0 = next_act[b * Mq + lane], a1 = next_act[b * Mq + lane + 64];
  float t0 = (e0 / s) * a0, t1 = (e1 / s) * a1;
  float s2 = t0 + t1;
#pragma unroll
  for (int off = 32; off; off >>= 1) s2 += __shfl_xor(s2, off);
  s2 += 1e-10f;
  p[lane]      = t0 / s2;
  p[lane + 64] = t1 / s2;
}

// ---------------- K3: aggregation, depth-3 pipelined MFMA (ascending) ----------------
__global__ __launch_bounds__(512, 2) void k3_aggregate(
    const float* __restrict__ input, const float* __restrict__ cur_act,
    const float* __restrict__ wgt, const float* __restrict__ qk,
    float* __restrict__ ncv) {
  const int mc = blockIdx.x;
  const int n0 = blockIdx.y * 16;
  const int t = threadIdx.x;
  const int w8 = t >> 6, l = t & 63;
  const int wv_m = w8 & 3, wv_b = w8 >> 2;
  const int lr = l & 15, g = l >> 4;
  const int m = mc * 4 + wv_m;
  __shared__ float Wf[4][32 * 256];   // 128 KB
  __shared__ float zl[16][4][64];     // 16 KB, persistent

  // pre-stage z = qk*cur_act (coalesced), once
#pragma unroll
  for (int p = 0; p < 2; ++p) {
    const int idx = t + p * 512;
    const int b = idx >> 4, nn = idx & 15;
    float4 q4 = *(const float4*)&qk[(size_t)b * NM + (size_t)(n0 + nn) * Mq + mc * 4];
    float ca = cur_act[b * Nq + n0 + nn];
    zl[nn][0][b] = q4.x * ca; zl[nn][1][b] = q4.y * ca;
    zl[nn][2][b] = q4.z * ca; zl[nn][3][b] = q4.w * ca;
  }
  __syncthreads();

  auto stageT = [&](int h) {           // ascending walk
    if (h > 31) return;
    const int nn = n0 + (h >> 1);
    const int ks = (h & 1) * 32;
    float* dst = &Wf[h & 3][0];
#pragma unroll
    for (int rr = 0; rr < 4; ++rr) {
      const int al = w8 * 4 + rr;
      const char* gs = (const char*)(wgt + (size_t)(nn * Aq + ks + al) * MD + mc * 256)
                       + ((l * 16) ^ (((al >> 3) & 1) << 6));
      dma16((const float*)gs, dst + al * 256);
    }
  };
  auto loadAv = [&](int h, float (&av)[2][8]) {
    if (h > 31) return;
    const int nn = n0 + (h >> 1);
    const int ks = (h & 1) * 32;
#pragma unroll
    for (int i = 0; i < 2; ++i) {
      const float* ap = input + (size_t)(32 * wv_b + 16 * i + lr) * NA + nn * Aq + ks + g * 8;
      *(float4*)&av[i][0] = *(const float4*)ap;
      *(float4*)&av[i][4] = *(const float4*)(ap + 4);
    }
  };
  auto mfmaPhase = [&](int h, float (&av)[2][8], float (&zr)[2], f32x4 (&acc)[2][4]) {
    bf16x8 af[2];
#pragma unroll
    for (int i = 0; i < 2; ++i) {
      float sv[8];
#pragma unroll
      for (int e = 0; e < 8; ++e) sv[e] = av[i][e] * zr[i];
      af[i] = pack8(sv);
    }
    const float* bufp = &Wf[h & 3][0];
#pragma unroll
    for (int j = 0; j < 4; ++j) {
      const int cx = (64 * wv_m + 16 * j + lr) ^ ((g & 1) << 4);
      float bv[8];
#pragma unroll
      for (int e = 0; e < 8; ++e) bv[e] = bufp[(g * 8 + e) * 256 + cx];
      bf16x8 bf = pack8(bv);
#pragma unroll
      for (int i = 0; i < 2; ++i)
        acc[i][j] = __builtin_amdgcn_mfma_f32_16x16x32_bf16(af[i], bf, acc[i][j], 0, 0, 0);
    }
  };

  float avE[2][8], avO[2][8];
  stageT(0);
  loadAv(0, avE);
  stageT(1);
  stageT(2);

  f32x4 acc[2][4];
#pragma unroll
  for (int i = 0; i < 2; ++i)
#pragma unroll
    for (int j = 0; j < 4; ++j) acc[i][j] = (f32x4)(0.0f);

  float zr[2];
  for (int hp = 0; hp < 16; ++hp) {
    const int h0 = hp * 2, h1 = h0 + 1;
    // ---- even phase ----
    if (hp == 0)      asm volatile("s_waitcnt vmcnt(8)" ::: "memory");
    else if (hp < 15) asm volatile("s_waitcnt vmcnt(4)" ::: "memory");
    else              asm volatile("s_waitcnt vmcnt(0)" ::: "memory");
    __builtin_amdgcn_s_barrier();
#pragma unroll
    for (int i = 0; i < 2; ++i) zr[i] = zl[hp][wv_m][32 * wv_b + 16 * i + lr];
    mfmaPhase(h0, avE, zr, acc);
    __builtin_amdgcn_sched_barrier(0);
    loadAv(h1, avO);
    __builtin_amdgcn_sched_barrier(0);
    stageT(h0 + 3);
    // ---- odd phase ----
    if (hp < 15) asm volatile("s_waitcnt vmcnt(4)" ::: "memory");
    else         asm volatile("s_waitcnt vmcnt(0)" ::: "memory");
    __builtin_amdgcn_s_barrier();
    mfmaPhase(h1, avO, zr, acc);
    __builtin_amdgcn_sched_barrier(0);
    loadAv(h0 + 2, avE);
    __builtin_amdgcn_sched_barrier(0);
    stageT(h1 + 3);
  }

  // epilogue: atomic partial sums over the 8 n-split blocks
#pragma unroll
  for (int i = 0; i < 2; ++i)
#pragma unroll
    for (int j = 0; j < 4; ++j) {
      const int d = 16 * j + lr;
#pragma unroll
      for (int r = 0; r < 4; ++r) {
        const int b = 32 * wv_b + 16 * i + 4 * g + r;
        atomicAdd(&ncv[(size_t)b * MD + m * Dq + d], acc[i][j][r]);
      }
    }
}

extern "C" void kernel_launch(void* const* d_in, const int* in_sizes, int n_in,
                              void* d_out, int out_size, void* d_ws, size_t ws_size,
                              hipStream_t stream) {
  const float* input    = (const float*)d_in[0];
  const float* cur_act  = (const float*)d_in[1];
  const float* ncvin    = (const float*)d_in[2];
  const float* next_act = (const float*)d_in[3];
  const float* wgt      = (const float*)d_in[4];
  // d_in[5] = num_iter (unused by reference)

  float* out = (float*)d_out;
  float* ncv = out;
  float* qk  = out + NCV_SZ + NA_SZ;

  k0_init<<<(NCV_SZ + NA_SZ + 255) / 256, 256, 0, stream>>>(out);
  k1_logits<<<dim3(32, 8), 512, 0, stream>>>(input, ncvin, wgt, qk);
  k2_softmax<<<(Bq * Nq) / 4, 256, 0, stream>>>(next_act, qk);
  k3_aggregate<<<dim3(32, 8), 512, 0, stream>>>(input, cur_act, wgt, qk, ncv);
}

// Round 13
// 147.542 us; speedup vs baseline: 1.0913x; 1.0913x over previous
//
#include <hip/hip_runtime.h>

// CapsuleFC: B=64, N=128, A=64, M=128, D=64
// out = [ncv (B*M*D) | na (B*M) | qk (B*N*M)], fp32
// R13: producer/consumer wave specialization. 768-thr blocks (12 waves):
// waves 8..11 = producers (pure DMA streamers, 4-tile ring, 32 DMAs in
// flight each, vmcnt(24) steady waits); waves 0..7 = consumers (MFMA,
// own-counter av/ncvin loads -> can never drain the prefetch queue).
typedef __attribute__((ext_vector_type(8))) short bf16x8;
typedef __attribute__((ext_vector_type(4))) float f32x4;

constexpr int Bq = 64, Nq = 128, Aq = 64, Mq = 128, Dq = 64;
constexpr int MD = Mq * Dq;    // 8192
constexpr int NM = Nq * Mq;    // 16384
constexpr int NA = Nq * Aq;    // 8192
constexpr int NCV_SZ = Bq * MD;   // 524288
constexpr int NA_SZ  = Bq * Mq;   // 8192
constexpr float SCALE = 0.125f;   // 1/sqrt(64)

__device__ __forceinline__ unsigned short f2b(float f) {  // fp32 -> bf16 RNE
  unsigned u = __float_as_uint(f);
  return (unsigned short)((u + 0x7fffu + ((u >> 16) & 1u)) >> 16);
}
__device__ __forceinline__ unsigned cvt2(float lo, float hi) {
  return ((unsigned)f2b(hi) << 16) | (unsigned)f2b(lo);
}
__device__ __forceinline__ bf16x8 pack8(const float* v) {
  union { unsigned u[4]; bf16x8 b; } x;
  x.u[0] = cvt2(v[0], v[1]); x.u[1] = cvt2(v[2], v[3]);
  x.u[2] = cvt2(v[4], v[5]); x.u[3] = cvt2(v[6], v[7]);
  return x.b;
}
__device__ __forceinline__ void dma16(const float* g, float* l) {
  __builtin_amdgcn_global_load_lds(
      (const __attribute__((address_space(1))) unsigned*)g,
      (__attribute__((address_space(3))) unsigned*)l, 16, 0, 0);
}

// ---------------- init: ncv = 0, na = 1 ----------------
__global__ __launch_bounds__(256) void k0_init(float* __restrict__ out) {
  int i = blockIdx.x * 256 + threadIdx.x;
  if (i < NCV_SZ) out[i] = 0.0f;
  else if (i < NCV_SZ + NA_SZ) out[i] = 1.0f;
}

// ---------------- K1: logits, producer/consumer MFMA ----------------
// grid (mc=32, ns=8), block 768. 16 n's / 32 half-tile phases, descending.
__global__ __launch_bounds__(768, 3) void k1_logits(
    const float* __restrict__ input, const float* __restrict__ ncvin,
    const float* __restrict__ wgt, float* __restrict__ logits) {
  const int mc = blockIdx.x;
  const int n0 = blockIdx.y * 16;
  const int t = threadIdx.x;
  const int w = t >> 6, l = t & 63;
  __shared__ float Wf[4][32 * 256];   // 128 KB, 4-tile ring

  if (w >= 8) {
    // ======== PRODUCER (waves 8..11): pure DMA streamer ========
    const int pw = w - 8;
    auto stageT = [&](int h) {        // descending walk: hh = 31-h
      const int hh = 31 - h;
      const int nn = n0 + (hh >> 1);
      const int ks = (hh & 1) * 32;
      float* dst = &Wf[h & 3][0];
#pragma unroll
      for (int rr = 0; rr < 8; ++rr) {
        const int al = pw * 8 + rr;
        const char* gs = (const char*)(wgt + (size_t)(nn * Aq + ks + al) * MD + mc * 256)
                         + ((l * 16) ^ (((al >> 3) & 1) << 6));
        dma16((const float*)gs, dst + al * 256);
      }
    };
    stageT(0); stageT(1); stageT(2); stageT(3);   // 32 DMAs in flight
    for (int h = 0; h < 32; ++h) {
      if (h <= 28)      asm volatile("s_waitcnt vmcnt(24)" ::: "memory");
      else if (h == 29) asm volatile("s_waitcnt vmcnt(16)" ::: "memory");
      else if (h == 30) asm volatile("s_waitcnt vmcnt(8)"  ::: "memory");
      else              asm volatile("s_waitcnt vmcnt(0)"  ::: "memory");
      __builtin_amdgcn_s_barrier();   // A: tile h landed
      __builtin_amdgcn_s_barrier();   // B: consumers done reading buf[h&3]
      if (h + 4 < 32) stageT(h + 4);  // refill ring
    }
  } else {
    // ======== CONSUMER (waves 0..7): MFMA + epilogue ========
    const int wv_m = w & 3, wv_b = w >> 2;
    const int lr = l & 15, g = l >> 4;
    const int m = mc * 4 + wv_m;

    float cnv[2][4][4];               // ncvin fragment (own counter, preloaded)
#pragma unroll
    for (int i = 0; i < 2; ++i)
#pragma unroll
      for (int j = 0; j < 4; ++j)
#pragma unroll
        for (int r = 0; r < 4; ++r)
          cnv[i][j][r] = ncvin[(size_t)(32 * wv_b + 16 * i + 4 * g + r) * MD + m * Dq + 16 * j + lr];

    auto loadAv = [&](int h, float (&av)[2][8]) {
      if (h > 31) return;
      const int hh = 31 - h;
      const int nn = n0 + (hh >> 1);
      const int ks = (hh & 1) * 32;
#pragma unroll
      for (int i = 0; i < 2; ++i) {
        const float* ap = input + (size_t)(32 * wv_b + 16 * i + lr) * NA + nn * Aq + ks + g * 8;
        *(float4*)&av[i][0] = *(const float4*)ap;
        *(float4*)&av[i][4] = *(const float4*)(ap + 4);
      }
    };
    auto mfmaPhase = [&](int h, float (&av)[2][8], f32x4 (&acc)[2][4]) {
      bf16x8 af[2];
#pragma unroll
      for (int i = 0; i < 2; ++i) af[i] = pack8(av[i]);
      const float* bufp = &Wf[h & 3][0];
#pragma unroll
      for (int j = 0; j < 4; ++j) {
        const int cx = (64 * wv_m + 16 * j + lr) ^ ((g & 1) << 4);
        float bv[8];
#pragma unroll
        for (int e = 0; e < 8; ++e) bv[e] = bufp[(g * 8 + e) * 256 + cx];
        bf16x8 bf = pack8(bv);
#pragma unroll
        for (int i = 0; i < 2; ++i)
          acc[i][j] = __builtin_amdgcn_mfma_f32_16x16x32_bf16(af[i], bf, acc[i][j], 0, 0, 0);
      }
    };

    float avE[2][8], avO[2][8];
    loadAv(0, avE);
    f32x4 acc[2][4];
    for (int h = 0; h < 32; ++h) {
      __builtin_amdgcn_s_barrier();   // A: buf[h&3] ready
      if ((h & 1) == 0) {
#pragma unroll
        for (int i = 0; i < 2; ++i)
#pragma unroll
          for (int j = 0; j < 4; ++j) acc[i][j] = (f32x4)(0.0f);
        loadAv(h + 1, avO);           // prefetch next av (own counter)
        mfmaPhase(h, avE, acc);
      } else {
        loadAv(h + 1, avE);
        mfmaPhase(h, avO, acc);
        {   // epilogue for this nn (register-only + shfl + one store)
          const int nn = n0 + ((31 - h) >> 1);
          float lp[2][4];
#pragma unroll
          for (int i = 0; i < 2; ++i)
#pragma unroll
            for (int r = 0; r < 4; ++r) lp[i][r] = 0.0f;
#pragma unroll
          for (int i = 0; i < 2; ++i)
#pragma unroll
            for (int j = 0; j < 4; ++j)
#pragma unroll
              for (int r = 0; r < 4; ++r)
                lp[i][r] = fmaf(acc[i][j][r], cnv[i][j][r], lp[i][r]);
#pragma unroll
          for (int off = 1; off < 16; off <<= 1)
#pragma unroll
            for (int i = 0; i < 2; ++i)
#pragma unroll
              for (int r = 0; r < 4; ++r) lp[i][r] += __shfl_xor(lp[i][r], off);
          float ov = lp[0][0];
#pragma unroll
          for (int i = 0; i < 2; ++i)
#pragma unroll
            for (int r = 0; r < 4; ++r)
              ov = (lr == i * 4 + r) ? lp[i][r] : ov;
          if (lr < 8) {
            const int b = 32 * wv_b + 16 * (lr >> 2) + 4 * g + (lr & 3);
            logits[(size_t)b * NM + (size_t)nn * Mq + m] = SCALE * ov;
          }
        }
      }
      __builtin_amdgcn_s_barrier();   // B: done reading buf[h&3]
    }
  }
}

// ---------------- K2: softmax + act modulation + renorm (in place) ----------------
__global__ __launch_bounds__(256) void k2_softmax(
    const float* __restrict__ next_act, float* __restrict__ qk) {
  const int row  = blockIdx.x * 4 + (threadIdx.x >> 6);
  const int lane = threadIdx.x & 63;
  const int b = row >> 7;
  float* p = qk + (size_t)row * Mq;
  float x0 = p[lane], x1 = p[lane + 64];
  float mx = fmaxf(x0, x1);
#pragma unroll
  for (int off = 32; off; off >>= 1) mx = fmaxf(mx, __shfl_xor(mx, off));
  float e0 = __expf(x0 - mx), e1 = __expf(x1 - mx);
  float s = e0 + e1;
#pragma unroll
  for (int off = 32; off; off >>= 1) s += __shfl_xor(s, off);
  float a0 = next_act[b * Mq + lane], a1 = next_act[b * Mq + lane + 64];
  float t0 = (e0 / s) * a0, t1 = (e1 / s) * a1;
  float s2 = t0 + t1;
#pragma unroll
  for (int off = 32; off; off >>= 1) s2 += __shfl_xor(s2, off);
  s2 += 1e-10f;
  p[lane]      = t0 / s2;
  p[lane + 64] = t1 / s2;
}

// ---------------- K3: aggregation, producer/consumer MFMA (ascending) ----------------
__global__ __launch_bounds__(768, 3) void k3_aggregate(
    const float* __restrict__ input, const float* __restrict__ cur_act,
    const float* __restrict__ wgt, const float* __restrict__ qk,
    float* __restrict__ ncv) {
  const int mc = blockIdx.x;
  const int n0 = blockIdx.y * 16;
  const int t = threadIdx.x;
  const int w = t >> 6, l = t & 63;
  __shared__ float Wf[4][32 * 256];   // 128 KB
  __shared__ float zl[16][4][64];     // 16 KB

  if (w >= 8) {
    // ======== PRODUCER ========
    const int pw = w - 8;
    auto stageT = [&](int h) {        // ascending walk
      const int nn = n0 + (h >> 1);
      const int ks = (h & 1) * 32;
      float* dst = &Wf[h & 3][0];
#pragma unroll
      for (int rr = 0; rr < 8; ++rr) {
        const int al = pw * 8 + rr;
        const char* gs = (const char*)(wgt + (size_t)(nn * Aq + ks + al) * MD + mc * 256)
                         + ((l * 16) ^ (((al >> 3) & 1) << 6));
        dma16((const float*)gs, dst + al * 256);
      }
    };
    stageT(0); stageT(1); stageT(2); stageT(3);
    for (int h = 0; h < 32; ++h) {
      if (h <= 28)      asm volatile("s_waitcnt vmcnt(24)" ::: "memory");
      else if (h == 29) asm volatile("s_waitcnt vmcnt(16)" ::: "memory");
      else if (h == 30) asm volatile("s_waitcnt vmcnt(8)"  ::: "memory");
      else              asm volatile("s_waitcnt vmcnt(0)"  ::: "memory");
      __builtin_amdgcn_s_barrier();   // A
      __builtin_amdgcn_s_barrier();   // B
      if (h + 4 < 32) stageT(h + 4);
    }
  } else {
    // ======== CONSUMER ========
    const int wv_m = w & 3, wv_b = w >> 2;
    const int lr = l & 15, g = l >> 4;
    const int m = mc * 4 + wv_m;

    // stage z = qk*cur_act (consumer threads: 512 -> 1024 entries, 2 each)
#pragma unroll
    for (int p = 0; p < 2; ++p) {
      const int idx = w * 64 + l + p * 512;
      const int b = idx >> 4, nn = idx & 15;
      float4 q4 = *(const float4*)&qk[(size_t)b * NM + (size_t)(n0 + nn) * Mq + mc * 4];
      float ca = cur_act[b * Nq + n0 + nn];
      zl[nn][0][b] = q4.x * ca; zl[nn][1][b] = q4.y * ca;
      zl[nn][2][b] = q4.z * ca; zl[nn][3][b] = q4.w * ca;
    }
    asm volatile("s_waitcnt lgkmcnt(0)" ::: "memory");  // zl visible before A(0)

    auto loadAv = [&](int h, float (&av)[2][8]) {
      if (h > 31) return;
      const int nn = n0 + (h >> 1);
      const int ks = (h & 1) * 32;
#pragma unroll
      for (int i = 0; i < 2; ++i) {
        const float* ap = input + (size_t)(32 * wv_b + 16 * i + lr) * NA + nn * Aq + ks + g * 8;
        *(float4*)&av[i][0] = *(const float4*)ap;
        *(float4*)&av[i][4] = *(const float4*)(ap + 4);
      }
    };
    auto mfmaPhase = [&](int h, float (&av)[2][8], float (&zr)[2], f32x4 (&acc)[2][4]) {
      bf16x8 af[2];
#pragma unroll
      for (int i = 0; i < 2; ++i) {
        float sv[8];
#pragma unroll
        for (int e = 0; e < 8; ++e) sv[e] = av[i][e] * zr[i];
        af[i] = pack8(sv);
      }
      const float* bufp = &Wf[h & 3][0];
#pragma unroll
      for (int j = 0; j < 4; ++j) {
        const int cx = (64 * wv_m + 16 * j + lr) ^ ((g & 1) << 4);
        float bv[8];
#pragma unroll
        for (int e = 0; e < 8; ++e) bv[e] = bufp[(g * 8 + e) * 256 + cx];
        bf16x8 bf = pack8(bv);
#pragma unroll
        for (int i = 0; i < 2; ++i)
          acc[i][j] = __builtin_amdgcn_mfma_f32_16x16x32_bf16(af[i], bf, acc[i][j], 0, 0, 0);
      }
    };

    float avE[2][8], avO[2][8];
    loadAv(0, avE);
    f32x4 acc[2][4];
#pragma unroll
    for (int i = 0; i < 2; ++i)
#pragma unroll
      for (int j = 0; j < 4; ++j) acc[i][j] = (f32x4)(0.0f);

    float zr[2];
    for (int h = 0; h < 32; ++h) {
      __builtin_amdgcn_s_barrier();   // A
      if ((h & 1) == 0) {
#pragma unroll
        for (int i = 0; i < 2; ++i) zr[i] = zl[h >> 1][wv_m][32 * wv_b + 16 * i + lr];
        loadAv(h + 1, avO);
        mfmaPhase(h, avE, zr, acc);
      } else {
        loadAv(h + 1, avE);
        mfmaPhase(h, avO, zr, acc);
      }
      __builtin_amdgcn_s_barrier();   // B
    }

    // epilogue: atomic partial sums over the 8 n-split blocks
#pragma unroll
    for (int i = 0; i < 2; ++i)
#pragma unroll
      for (int j = 0; j < 4; ++j) {
        const int d = 16 * j + lr;
#pragma unroll
        for (int r = 0; r < 4; ++r) {
          const int b = 32 * wv_b + 16 * i + 4 * g + r;
          atomicAdd(&ncv[(size_t)b * MD + m * Dq + d], acc[i][j][r]);
        }
      }
  }
}

extern "C" void kernel_launch(void* const* d_in, const int* in_sizes, int n_in,
                              void* d_out, int out_size, void* d_ws, size_t ws_size,
                              hipStream_t stream) {
  const float* input    = (const float*)d_in[0];
  const float* cur_act  = (const float*)d_in[1];
  const float* ncvin    = (const float*)d_in[2];
  const float* next_act = (const float*)d_in[3];
  const float* wgt      = (const float*)d_in[4];
  // d_in[5] = num_iter (unused by reference)

  float* out = (float*)d_out;
  float* ncv = out;
  float* qk  = out + NCV_SZ + NA_SZ;

  k0_init<<<(NCV_SZ + NA_SZ + 255) / 256, 256, 0, stream>>>(out);
  k1_logits<<<dim3(32, 8), 768, 0, stream>>>(input, ncvin, wgt, qk);
  k2_softmax<<<(Bq * Nq) / 4, 256, 0, stream>>>(next_act, qk);
  k3_aggregate<<<dim3(32, 8), 768, 0, stream>>>(input, cur_act, wgt, qk, ncv);
}